// Round 2
// baseline (470.650 us; speedup 1.0000x reference)
//
#include <hip/hip_runtime.h>

// Problem: M=65536, K=512, N=512
//   x_scale = max(|x|)/127 (>= 1e-5); x_int8 = clip(rint(x/x_scale));
//   out = (x_int8 @ W^T).f32 * (x_scale * wscale[n])
// NOTE: harness delivers integer inputs as int32 — weight arrives as 1 MB of
// int32 in [-128,127]; we repack to int8 in d_ws each launch.

#define M_DIM 65536
#define K_DIM 512
#define N_DIM 512
#define EPSF  1e-5f

typedef int int32x4 __attribute__((ext_vector_type(4)));

// ---------------- Kernel 1: global absmax of x ----------------
__global__ void absmax_kernel(const float* __restrict__ x,
                              unsigned int* __restrict__ ws, int n4) {
    const float4* x4 = (const float4*)x;
    int i = blockIdx.x * blockDim.x + threadIdx.x;
    int stride = gridDim.x * blockDim.x;
    float m = 0.0f;
    for (; i < n4; i += stride) {
        float4 v = x4[i];
        m = fmaxf(m, fmaxf(fmaxf(fabsf(v.x), fabsf(v.y)),
                           fmaxf(fabsf(v.z), fabsf(v.w))));
    }
    #pragma unroll
    for (int off = 32; off > 0; off >>= 1)
        m = fmaxf(m, __shfl_xor(m, off));
    if ((threadIdx.x & 63) == 0)
        atomicMax(ws, __float_as_uint(m));  // positive floats monotonic as uint
}

// ---------------- Kernel 2: repack int32 weights -> int8 ----------------
__global__ void pack_kernel(const int* __restrict__ wi,
                            unsigned int* __restrict__ wp, int n4) {
    int i = blockIdx.x * blockDim.x + threadIdx.x;
    if (i < n4) {
        int4 v = ((const int4*)wi)[i];
        wp[i] = (v.x & 0xff) | ((v.y & 0xff) << 8) |
                ((v.z & 0xff) << 16) | ((unsigned)v.w << 24);
    }
}

// quantize 4 floats -> 4 packed int8 via round-to-nearest-even magic constant.
// |x*inv| <= ~127.00002 by construction, so no clamp needed; low 8 bits of the
// f32 mantissa of (t + 1.5*2^23) are t's two's-complement int8.
__device__ inline unsigned int quantpack4(float4 f, float inv) {
    const float C = 12582912.0f;  // 1.5 * 2^23
    unsigned int u0 = __float_as_uint(fmaf(f.x, inv, C));
    unsigned int u1 = __float_as_uint(fmaf(f.y, inv, C));
    unsigned int u2 = __float_as_uint(fmaf(f.z, inv, C));
    unsigned int u3 = __float_as_uint(fmaf(f.w, inv, C));
    return (u0 & 0xffu) | ((u1 & 0xffu) << 8) | ((u2 & 0xffu) << 16) | (u3 << 24);
}

// ---------------- Kernel 3: fused quantize + int8 GEMM + dequant ----------------
// Block: 256 threads = 4 waves. Each wave: 16 rows x 128 cols output strip.
// grid = (N/128, M/64). No LDS: packed weight (256 KB) is L2-resident; x
// fragments are loaded fp32, quantized in-register per K-step.
__global__ __launch_bounds__(256) void gemm_kernel(
    const float* __restrict__ x, const signed char* __restrict__ w,
    const float* __restrict__ wscale, const unsigned int* __restrict__ ws,
    float* __restrict__ out) {
    const int wave = threadIdx.x >> 6;
    const int lane = threadIdx.x & 63;
    const int quad = lane >> 4;   // 0..3
    const int l16  = lane & 15;   // 0..15

    float mx  = __uint_as_float(ws[0]);
    float s   = fmaxf(mx / 127.0f, EPSF);
    float inv = 1.0f / s;

    const int m0 = blockIdx.y * 64 + wave * 16;  // wave's 16-row strip
    const int n0 = blockIdx.x * 128;

    // A-fragment: row m = m0 + l16, k = k0 + quad*16 + j (16 contiguous)
    const float* xrow = x + (long)(m0 + l16) * K_DIM + quad * 16;

    int32x4 acc[8] = {};

    #pragma unroll
    for (int k0 = 0; k0 < K_DIM; k0 += 64) {
        const float4* xp = (const float4*)(xrow + k0);
        float4 f0 = xp[0], f1 = xp[1], f2 = xp[2], f3 = xp[3];
        int32x4 a;
        a.x = (int)quantpack4(f0, inv);
        a.y = (int)quantpack4(f1, inv);
        a.z = (int)quantpack4(f2, inv);
        a.w = (int)quantpack4(f3, inv);

        const signed char* wk = w + k0 + quad * 16;
        #pragma unroll
        for (int t = 0; t < 8; ++t) {
            // B-fragment: col n = n0 + t*16 + l16, same 16 contiguous k bytes
            int32x4 b = *(const int32x4*)(wk + (long)(n0 + t * 16 + l16) * K_DIM);
            acc[t] = __builtin_amdgcn_mfma_i32_16x16x64_i8(a, b, acc[t], 0, 0, 0);
        }
    }

    // Epilogue. C/D layout: col = lane&15, row = quad*4 + reg (dtype-independent).
    #pragma unroll
    for (int t = 0; t < 8; ++t) {
        int n = n0 + t * 16 + l16;
        float c = s * wscale[n];
        float* orow = out + (long)(m0 + quad * 4) * N_DIM + n;
        #pragma unroll
        for (int r = 0; r < 4; ++r)
            orow[(long)r * N_DIM] = (float)acc[t][r] * c;
    }
}

extern "C" void kernel_launch(void* const* d_in, const int* in_sizes, int n_in,
                              void* d_out, int out_size, void* d_ws, size_t ws_size,
                              hipStream_t stream) {
    const float* x   = (const float*)d_in[0];
    const int*   wi  = (const int*)d_in[1];    // int8 values stored as int32
    const float* sc  = (const float*)d_in[2];
    float*       out = (float*)d_out;

    unsigned int* ws_abs = (unsigned int*)d_ws;           // [0]: absmax bits
    unsigned int* wp     = (unsigned int*)((char*)d_ws + 256);  // packed W, 256 KB
    const signed char* w8 = (const signed char*)wp;

    hipMemsetAsync(ws_abs, 0, sizeof(unsigned int), stream);

    const int n4x = (M_DIM * K_DIM) / 4;  // 8388608 float4s
    absmax_kernel<<<2048, 256, 0, stream>>>(x, ws_abs, n4x);

    const int n4w = (N_DIM * K_DIM) / 4;  // 65536 packed dwords
    pack_kernel<<<n4w / 256, 256, 0, stream>>>(wi, wp, n4w);

    dim3 grid(N_DIM / 128, M_DIM / 64, 1);  // (4, 1024)
    gemm_kernel<<<grid, dim3(256), 0, stream>>>(x, w8, sc, ws_abs, out);
}

// Round 3
// 447.080 us; speedup vs baseline: 1.0527x; 1.0527x over previous
//
#include <hip/hip_runtime.h>

// Problem: M=65536, K=512, N=512
//   x_scale = max(|x|)/127 (>= 1e-5); x_int8 = clip(rint(x/x_scale));
//   out = (x_int8 @ W^T).f32 * (x_scale * wscale[n])
// Harness delivers integer inputs as int32 (1 MB weight) -> repack to int8 in ws.

#define M_DIM 65536
#define K_DIM 512
#define N_DIM 512
#define EPSF  1e-5f

typedef int int32x4 __attribute__((ext_vector_type(4)));

// ---------------- Kernel 1: global absmax of x ----------------
// 4096 blocks x 256 threads; each thread 8 independent float4 loads (deep MLP).
__global__ void absmax_kernel(const float* __restrict__ x,
                              unsigned int* __restrict__ ws) {
    const float4* x4 = (const float4*)x;
    const int STRIDE = 4096 * 256;              // threads total
    int i = blockIdx.x * 256 + threadIdx.x;
    float m = 0.0f;
    #pragma unroll
    for (int j = 0; j < 8; ++j) {               // 8 * 1M = 8.4M float4
        float4 v = x4[i + j * STRIDE];
        m = fmaxf(m, fmaxf(fmaxf(fabsf(v.x), fabsf(v.y)),
                           fmaxf(fabsf(v.z), fabsf(v.w))));
    }
    #pragma unroll
    for (int off = 32; off > 0; off >>= 1)
        m = fmaxf(m, __shfl_xor(m, off));
    if ((threadIdx.x & 63) == 0)
        atomicMax(ws, __float_as_uint(m));      // fp32>=0 monotonic as uint
}

// ---------------- Kernel 2: repack int32 weights -> int8 ----------------
__global__ void pack_kernel(const int* __restrict__ wi,
                            unsigned int* __restrict__ wp, int n4) {
    int i = blockIdx.x * blockDim.x + threadIdx.x;
    if (i < n4) {
        int4 v = ((const int4*)wi)[i];
        wp[i] = (v.x & 0xff) | ((v.y & 0xff) << 8) |
                ((v.z & 0xff) << 16) | ((unsigned)v.w << 24);
    }
}

// quantize 4 floats -> 4 packed int8 (RNE magic constant; no clamp needed
// since |x*inv| <= ~127.00002). v_perm packs bytes in 3 ops.
__device__ inline unsigned int quantpack4(float4 f, float inv) {
    const float C = 12582912.0f;  // 1.5 * 2^23
    unsigned int u0 = __float_as_uint(fmaf(f.x, inv, C));
    unsigned int u1 = __float_as_uint(fmaf(f.y, inv, C));
    unsigned int u2 = __float_as_uint(fmaf(f.z, inv, C));
    unsigned int u3 = __float_as_uint(fmaf(f.w, inv, C));
    unsigned int lo = __builtin_amdgcn_perm(u1, u0, 0x0C0C0400u); // [u0b0,u1b0,0,0]
    unsigned int hi = __builtin_amdgcn_perm(u3, u2, 0x04000C0Cu); // [0,0,u2b0,u3b0]
    return lo | hi;
}

// ---------------- Kernel 3: fused quantize + int8 GEMM + dequant ----------------
// 256 threads = 4 waves. Block tile 128M x 128N; wave tile 32M x 128N.
// B (128 cols x 512 k int8 = 64 KB) staged once into LDS in FRAGMENT order via
// per-lane-gather global_load_lds -> K-loop B reads are lane-contiguous
// ds_read_b128 (conflict-free). x read direct from global (full 64B lines).
__global__ __launch_bounds__(256, 2) void gemm_kernel(
    const float* __restrict__ x, const signed char* __restrict__ w,
    const float* __restrict__ wscale, const unsigned int* __restrict__ ws,
    float* __restrict__ out) {
    __shared__ signed char Blds[64 * 1024];

    const int wave = threadIdx.x >> 6;
    const int lane = threadIdx.x & 63;
    const int quad = lane >> 4;   // 0..3
    const int l16  = lane & 15;   // 0..15

    // XCD swizzle: 2048 blocks; all 4 N-blocks of one M-strip on one XCD,
    // contiguous M region per XCD.
    const int id  = blockIdx.x;          // 0..2047
    const int xcd = id & 7;
    const int j   = id >> 3;             // 0..255
    const int by  = xcd * 64 + (j >> 2); // 0..511
    const int bx  = j & 3;               // 0..3
    const int m0 = by * 128;
    const int n0 = bx * 128;

    // ---- stage B into LDS, fragment order: [c=k/64][t=n-tile][lane][16B] ----
    // wave w stages c = 2w, 2w+1; each instr: 64 lanes gather their own
    // fragment (row n0+t*16+l16, bytes c*64+quad*16..+16) -> base + lane*16.
    #pragma unroll
    for (int cc = 0; cc < 2; ++cc) {
        int c = wave * 2 + cc;
        #pragma unroll
        for (int t = 0; t < 8; ++t) {
            const signed char* g = w + (long)(n0 + t * 16 + l16) * K_DIM
                                     + c * 64 + quad * 16;
            __builtin_amdgcn_global_load_lds(
                (const __attribute__((address_space(1))) unsigned int*)g,
                (__attribute__((address_space(3))) unsigned int*)(Blds + (c * 8 + t) * 1024),
                16, 0, 0);
        }
    }

    float mx  = __uint_as_float(ws[0]);
    float s   = fmaxf(mx / 127.0f, EPSF);
    float inv = 1.0f / s;

    // A rows: wave covers m0 + wave*32 .. +32 (two 16-row fragments)
    const int mw = m0 + wave * 32;
    const float* xr0 = x + (long)(mw + l16) * K_DIM + quad * 16;
    const float* xr1 = xr0 + (long)16 * K_DIM;

    int32x4 acc0[8] = {};
    int32x4 acc1[8] = {};

    __syncthreads();  // waits vmcnt(0) -> LDS staging complete

    #pragma unroll
    for (int k0 = 0; k0 < K_DIM; k0 += 64) {
        const float4* xp0 = (const float4*)(xr0 + k0);
        const float4* xp1 = (const float4*)(xr1 + k0);
        float4 f0 = xp0[0], f1 = xp0[1], f2 = xp0[2], f3 = xp0[3];
        float4 g0 = xp1[0], g1 = xp1[1], g2 = xp1[2], g3 = xp1[3];
        int32x4 a0, a1;
        a0.x = (int)quantpack4(f0, inv);
        a0.y = (int)quantpack4(f1, inv);
        a0.z = (int)quantpack4(f2, inv);
        a0.w = (int)quantpack4(f3, inv);
        a1.x = (int)quantpack4(g0, inv);
        a1.y = (int)quantpack4(g1, inv);
        a1.z = (int)quantpack4(g2, inv);
        a1.w = (int)quantpack4(g3, inv);

        const signed char* bbase = Blds + (k0 >> 6) * 8192 + lane * 16;
        #pragma unroll
        for (int t = 0; t < 8; ++t) {
            int32x4 b = *(const int32x4*)(bbase + t * 1024);
            acc0[t] = __builtin_amdgcn_mfma_i32_16x16x64_i8(a0, b, acc0[t], 0, 0, 0);
            acc1[t] = __builtin_amdgcn_mfma_i32_16x16x64_i8(a1, b, acc1[t], 0, 0, 0);
        }
    }

    // Epilogue. C/D layout: col = lane&15, row = quad*4 + reg.
    #pragma unroll
    for (int t = 0; t < 8; ++t) {
        int n = n0 + t * 16 + l16;
        float c = s * wscale[n];
        float* o0 = out + (long)(mw + quad * 4) * N_DIM + n;
        float* o1 = o0 + (long)16 * N_DIM;
        #pragma unroll
        for (int r = 0; r < 4; ++r) {
            o0[(long)r * N_DIM] = (float)acc0[t][r] * c;
            o1[(long)r * N_DIM] = (float)acc1[t][r] * c;
        }
    }
}

extern "C" void kernel_launch(void* const* d_in, const int* in_sizes, int n_in,
                              void* d_out, int out_size, void* d_ws, size_t ws_size,
                              hipStream_t stream) {
    const float* x   = (const float*)d_in[0];
    const int*   wi  = (const int*)d_in[1];    // int8 values stored as int32
    const float* sc  = (const float*)d_in[2];
    float*       out = (float*)d_out;

    unsigned int* ws_abs = (unsigned int*)d_ws;                 // [0]: absmax bits
    unsigned int* wp     = (unsigned int*)((char*)d_ws + 256);  // packed W, 256 KB
    const signed char* w8 = (const signed char*)wp;

    hipMemsetAsync(ws_abs, 0, sizeof(unsigned int), stream);

    absmax_kernel<<<4096, 256, 0, stream>>>(x, ws_abs);

    const int n4w = (N_DIM * K_DIM) / 4;  // 65536 packed dwords
    pack_kernel<<<n4w / 256, 256, 0, stream>>>(wi, wp, n4w);

    gemm_kernel<<<2048, 256, 0, stream>>>(x, w8, sc, ws_abs, out);
}

// Round 4
// 300.109 us; speedup vs baseline: 1.5683x; 1.4897x over previous
//
#include <hip/hip_runtime.h>

// Problem: M=65536, K=512, N=512
//   x_scale = max(|x|)/127 (>= 1e-5); x_int8 = clip(rint(x/x_scale));
//   out = (x_int8 @ W^T).f32 * (x_scale * wscale[n])
// Harness delivers integer inputs as int32 (1 MB weight) -> repack to int8 in ws.
// R4: absmax via two-stage atomic-free reduction (R3's single-address atomicMax
// from 16K waves serialized at the coherence point -> 194 us tail).

#define M_DIM 65536
#define K_DIM 512
#define N_DIM 512
#define EPSF  1e-5f

typedef int int32x4 __attribute__((ext_vector_type(4)));

// ---------------- Kernel 1a: per-block absmax partials ----------------
// 4096 blocks x 256 threads; block b reduces a contiguous 32 KB chunk.
__global__ void absmax1_kernel(const float* __restrict__ x,
                               float* __restrict__ partials) {
    __shared__ float red[4];
    const float4* x4 = (const float4*)x;
    const int base = blockIdx.x * 2048;          // float4 units; 2048*16B = 32KB
    const int t = threadIdx.x;
    float m = 0.0f;
    #pragma unroll
    for (int j = 0; j < 8; ++j) {                // 8 contiguous 4KB sweeps
        float4 v = x4[base + j * 256 + t];
        m = fmaxf(m, fmaxf(fmaxf(fabsf(v.x), fabsf(v.y)),
                           fmaxf(fabsf(v.z), fabsf(v.w))));
    }
    #pragma unroll
    for (int off = 32; off > 0; off >>= 1)
        m = fmaxf(m, __shfl_xor(m, off));
    if ((t & 63) == 0) red[t >> 6] = m;
    __syncthreads();
    if (t == 0)
        partials[blockIdx.x] = fmaxf(fmaxf(red[0], red[1]),
                                     fmaxf(red[2], red[3]));
}

// ---------------- Kernel 1b: reduce 4096 partials -> ws[0] ----------------
__global__ void absmax2_kernel(const float* __restrict__ partials,
                               unsigned int* __restrict__ ws) {
    __shared__ float red[4];
    const int t = threadIdx.x;
    const float4* p4 = (const float4*)partials;
    float m = 0.0f;
    #pragma unroll
    for (int j = 0; j < 4; ++j) {                // 256 threads * 4 float4 = 4096
        float4 v = p4[t + j * 256];
        m = fmaxf(m, fmaxf(fmaxf(v.x, v.y), fmaxf(v.z, v.w)));
    }
    #pragma unroll
    for (int off = 32; off > 0; off >>= 1)
        m = fmaxf(m, __shfl_xor(m, off));
    if ((t & 63) == 0) red[t >> 6] = m;
    __syncthreads();
    if (t == 0) {
        float r = fmaxf(fmaxf(red[0], red[1]), fmaxf(red[2], red[3]));
        ws[0] = __float_as_uint(r);
    }
}

// ---------------- Kernel 2: repack int32 weights -> int8 ----------------
__global__ void pack_kernel(const int* __restrict__ wi,
                            unsigned int* __restrict__ wp, int n4) {
    int i = blockIdx.x * blockDim.x + threadIdx.x;
    if (i < n4) {
        int4 v = ((const int4*)wi)[i];
        wp[i] = (v.x & 0xff) | ((v.y & 0xff) << 8) |
                ((v.z & 0xff) << 16) | ((unsigned)v.w << 24);
    }
}

// quantize 4 floats -> 4 packed int8 (RNE magic constant; no clamp needed
// since |x*inv| <= ~127.00002). v_perm packs bytes in 2 ops.
__device__ inline unsigned int quantpack4(float4 f, float inv) {
    const float C = 12582912.0f;  // 1.5 * 2^23
    unsigned int u0 = __float_as_uint(fmaf(f.x, inv, C));
    unsigned int u1 = __float_as_uint(fmaf(f.y, inv, C));
    unsigned int u2 = __float_as_uint(fmaf(f.z, inv, C));
    unsigned int u3 = __float_as_uint(fmaf(f.w, inv, C));
    unsigned int lo = __builtin_amdgcn_perm(u1, u0, 0x0C0C0400u); // [u0b0,u1b0,0,0]
    unsigned int hi = __builtin_amdgcn_perm(u3, u2, 0x04000C0Cu); // [0,0,u2b0,u3b0]
    return lo | hi;
}

// ---------------- Kernel 3: fused quantize + int8 GEMM + dequant ----------------
// 256 threads = 4 waves. Block tile 128M x 128N; wave tile 32M x 128N.
// B (128 cols x 512 k int8 = 64 KB) staged once into LDS in FRAGMENT order via
// per-lane-gather global_load_lds -> K-loop B reads are lane-contiguous
// ds_read_b128 (conflict-free). x read direct from global (full 64B lines).
__global__ __launch_bounds__(256, 2) void gemm_kernel(
    const float* __restrict__ x, const signed char* __restrict__ w,
    const float* __restrict__ wscale, const unsigned int* __restrict__ ws,
    float* __restrict__ out) {
    __shared__ signed char Blds[64 * 1024];

    const int wave = threadIdx.x >> 6;
    const int lane = threadIdx.x & 63;
    const int quad = lane >> 4;   // 0..3
    const int l16  = lane & 15;   // 0..15

    // XCD swizzle: 2048 blocks; all 4 N-blocks of one M-strip on one XCD,
    // contiguous M region per XCD.
    const int id  = blockIdx.x;          // 0..2047
    const int xcd = id & 7;
    const int j   = id >> 3;             // 0..255
    const int by  = xcd * 64 + (j >> 2); // 0..511
    const int bx  = j & 3;               // 0..3
    const int m0 = by * 128;
    const int n0 = bx * 128;

    // ---- stage B into LDS, fragment order: [c=k/64][t=n-tile][lane][16B] ----
    #pragma unroll
    for (int cc = 0; cc < 2; ++cc) {
        int c = wave * 2 + cc;
        #pragma unroll
        for (int t = 0; t < 8; ++t) {
            const signed char* g = w + (long)(n0 + t * 16 + l16) * K_DIM
                                     + c * 64 + quad * 16;
            __builtin_amdgcn_global_load_lds(
                (const __attribute__((address_space(1))) unsigned int*)g,
                (__attribute__((address_space(3))) unsigned int*)(Blds + (c * 8 + t) * 1024),
                16, 0, 0);
        }
    }

    float mx  = __uint_as_float(ws[0]);
    float s   = fmaxf(mx / 127.0f, EPSF);
    float inv = 1.0f / s;

    // A rows: wave covers m0 + wave*32 .. +32 (two 16-row fragments)
    const int mw = m0 + wave * 32;
    const float* xr0 = x + (long)(mw + l16) * K_DIM + quad * 16;
    const float* xr1 = xr0 + (long)16 * K_DIM;

    int32x4 acc0[8] = {};
    int32x4 acc1[8] = {};

    __syncthreads();  // waits vmcnt(0) -> LDS staging complete

    #pragma unroll
    for (int k0 = 0; k0 < K_DIM; k0 += 64) {
        const float4* xp0 = (const float4*)(xr0 + k0);
        const float4* xp1 = (const float4*)(xr1 + k0);
        float4 f0 = xp0[0], f1 = xp0[1], f2 = xp0[2], f3 = xp0[3];
        float4 g0 = xp1[0], g1 = xp1[1], g2 = xp1[2], g3 = xp1[3];
        int32x4 a0, a1;
        a0.x = (int)quantpack4(f0, inv);
        a0.y = (int)quantpack4(f1, inv);
        a0.z = (int)quantpack4(f2, inv);
        a0.w = (int)quantpack4(f3, inv);
        a1.x = (int)quantpack4(g0, inv);
        a1.y = (int)quantpack4(g1, inv);
        a1.z = (int)quantpack4(g2, inv);
        a1.w = (int)quantpack4(g3, inv);

        const signed char* bbase = Blds + (k0 >> 6) * 8192 + lane * 16;
        #pragma unroll
        for (int t = 0; t < 8; ++t) {
            int32x4 b = *(const int32x4*)(bbase + t * 1024);
            acc0[t] = __builtin_amdgcn_mfma_i32_16x16x64_i8(a0, b, acc0[t], 0, 0, 0);
            acc1[t] = __builtin_amdgcn_mfma_i32_16x16x64_i8(a1, b, acc1[t], 0, 0, 0);
        }
    }

    // Epilogue. C/D layout: col = lane&15, row = quad*4 + reg.
    #pragma unroll
    for (int t = 0; t < 8; ++t) {
        int n = n0 + t * 16 + l16;
        float c = s * wscale[n];
        float* o0 = out + (long)(mw + quad * 4) * N_DIM + n;
        float* o1 = o0 + (long)16 * N_DIM;
        #pragma unroll
        for (int r = 0; r < 4; ++r) {
            o0[(long)r * N_DIM] = (float)acc0[t][r] * c;
            o1[(long)r * N_DIM] = (float)acc1[t][r] * c;
        }
    }
}

extern "C" void kernel_launch(void* const* d_in, const int* in_sizes, int n_in,
                              void* d_out, int out_size, void* d_ws, size_t ws_size,
                              hipStream_t stream) {
    const float* x   = (const float*)d_in[0];
    const int*   wi  = (const int*)d_in[1];    // int8 values stored as int32
    const float* sc  = (const float*)d_in[2];
    float*       out = (float*)d_out;

    unsigned int* ws_abs   = (unsigned int*)d_ws;                  // [0]: absmax bits
    float*        partials = (float*)((char*)d_ws + 256);          // 4096 floats
    unsigned int* wp       = (unsigned int*)((char*)d_ws + 32768); // packed W, 256 KB
    const signed char* w8  = (const signed char*)wp;

    absmax1_kernel<<<4096, 256, 0, stream>>>(x, partials);
    absmax2_kernel<<<1, 256, 0, stream>>>(partials, ws_abs);

    const int n4w = (N_DIM * K_DIM) / 4;  // 65536 packed dwords
    pack_kernel<<<n4w / 256, 256, 0, stream>>>(wi, wp, n4w);

    gemm_kernel<<<2048, 256, 0, stream>>>(x, w8, sc, ws_abs, out);
}

// Round 5
// 282.808 us; speedup vs baseline: 1.6642x; 1.0612x over previous
//
#include <hip/hip_runtime.h>

// Problem: M=65536, K=512, N=512
//   x_scale = max(|x|)/127 (>= 1e-5); x_int8 = clip(rint(x/x_scale));
//   out = (x_int8 @ W^T).f32 * (x_scale * wscale[n])
// Harness delivers integer inputs as int32 (1 MB weight) -> repack to int8.
// R5: pre-quantize x to int8 once (was re-read+re-quantized 4x inside gemm);
// gemm K-loop becomes 2 int8 VMEM + 8 ds_read + 16 MFMA per wave-iter.
// Pipeline: absmax1+pack -> quant (self-reduces partials, publishes scale)
//           -> gemm8.  Fallback to R4 path if ws_size < 34 MB.

#define M_DIM 65536
#define K_DIM 512
#define N_DIM 512
#define EPSF  1e-5f

typedef int int32x4 __attribute__((ext_vector_type(4)));

// ---- ws layout (bytes) ----
#define WS_PART   256                       // 4096 float partials (16 KB)
#define WS_WPACK  32768                     // packed int8 weight (256 KB)
#define WS_X8     294912                    // quantized x (33.5 MB)
#define WS_NEEDED ((size_t)WS_X8 + (size_t)M_DIM * K_DIM)

__device__ inline unsigned int pack_w4(int4 v) {
    return (v.x & 0xff) | ((v.y & 0xff) << 8) |
           ((v.z & 0xff) << 16) | ((unsigned)v.w << 24);
}

// quantize 4 floats -> 4 packed int8 (RNE magic constant; no clamp needed
// since |x*inv| <= ~127.00002).
__device__ inline unsigned int quantpack4(float4 f, float inv) {
    const float C = 12582912.0f;  // 1.5 * 2^23
    unsigned int u0 = __float_as_uint(fmaf(f.x, inv, C));
    unsigned int u1 = __float_as_uint(fmaf(f.y, inv, C));
    unsigned int u2 = __float_as_uint(fmaf(f.z, inv, C));
    unsigned int u3 = __float_as_uint(fmaf(f.w, inv, C));
    unsigned int lo = __builtin_amdgcn_perm(u1, u0, 0x0C0C0400u);
    unsigned int hi = __builtin_amdgcn_perm(u3, u2, 0x04000C0Cu);
    return lo | hi;
}

// ---------------- Kernel 1: absmax partials + weight repack (fused grid) ----
// blocks 0..4095: partial absmax of a contiguous 32 KB chunk of x.
// blocks 4096..4159: repack the 1 MB int32 weight into 256 KB int8.
__global__ void absmax1_pack_kernel(const float* __restrict__ x,
                                    const int* __restrict__ wi,
                                    float* __restrict__ partials,
                                    unsigned int* __restrict__ wp) {
    const int b = blockIdx.x;
    const int t = threadIdx.x;
    if (b < 4096) {
        __shared__ float red[4];
        const float4* x4 = (const float4*)x;
        const int base = b * 2048;               // float4 units (32 KB chunk)
        float m = 0.0f;
        #pragma unroll
        for (int j = 0; j < 8; ++j) {
            float4 v = x4[base + j * 256 + t];
            m = fmaxf(m, fmaxf(fmaxf(fabsf(v.x), fabsf(v.y)),
                               fmaxf(fabsf(v.z), fabsf(v.w))));
        }
        #pragma unroll
        for (int off = 32; off > 0; off >>= 1)
            m = fmaxf(m, __shfl_xor(m, off));
        if ((t & 63) == 0) red[t >> 6] = m;
        __syncthreads();
        if (t == 0)
            partials[b] = fmaxf(fmaxf(red[0], red[1]), fmaxf(red[2], red[3]));
    } else {
        const int bb = b - 4096;
        #pragma unroll
        for (int j = 0; j < 4; ++j) {
            int d = bb * 1024 + j * 256 + t;     // packed dword index
            wp[d] = pack_w4(((const int4*)wi)[d]);
        }
    }
}

// ---------------- Kernel 2: quantize x -> int8 (self-reduces partials) ------
// 2048 blocks; every block reduces the 4096 partials (16 KB, L2-broadcast),
// computes s, quantizes its 64 KB fp32 chunk -> 16 KB int8. Block 0 publishes
// s for the gemm.
__global__ void quant_kernel(const float* __restrict__ x,
                             const float* __restrict__ partials,
                             unsigned int* __restrict__ ws_abs,
                             unsigned int* __restrict__ x8) {
    __shared__ float red[4];
    const int t = threadIdx.x;
    const float4* p4 = (const float4*)partials;
    float m = 0.0f;
    #pragma unroll
    for (int j = 0; j < 4; ++j) {                // 1024 float4 = 4096 partials
        float4 v = p4[t + j * 256];
        m = fmaxf(m, fmaxf(fmaxf(v.x, v.y), fmaxf(v.z, v.w)));
    }
    #pragma unroll
    for (int off = 32; off > 0; off >>= 1)
        m = fmaxf(m, __shfl_xor(m, off));
    if ((t & 63) == 0) red[t >> 6] = m;
    __syncthreads();
    m = fmaxf(fmaxf(red[0], red[1]), fmaxf(red[2], red[3]));
    const float s   = fmaxf(m / 127.0f, EPSF);
    const float inv = 1.0f / s;
    if (blockIdx.x == 0 && t == 0) ws_abs[0] = __float_as_uint(s);

    const float4* x4 = (const float4*)x;
    const int base = blockIdx.x * 4096;          // float4 units (64 KB chunk)
    #pragma unroll
    for (int j = 0; j < 16; ++j) {
        int idx = base + j * 256 + t;
        x8[idx] = quantpack4(x4[idx], inv);      // coalesced dword stores
    }
}

// ---------------- Kernel 1b (fallback path): reduce partials -> mx bits -----
__global__ void absmax2_kernel(const float* __restrict__ partials,
                               unsigned int* __restrict__ ws) {
    __shared__ float red[4];
    const int t = threadIdx.x;
    const float4* p4 = (const float4*)partials;
    float m = 0.0f;
    #pragma unroll
    for (int j = 0; j < 4; ++j) {
        float4 v = p4[t + j * 256];
        m = fmaxf(m, fmaxf(fmaxf(v.x, v.y), fmaxf(v.z, v.w)));
    }
    #pragma unroll
    for (int off = 32; off > 0; off >>= 1)
        m = fmaxf(m, __shfl_xor(m, off));
    if ((t & 63) == 0) red[t >> 6] = m;
    __syncthreads();
    if (t == 0)
        ws[0] = __float_as_uint(fmaxf(fmaxf(red[0], red[1]),
                                      fmaxf(red[2], red[3])));
}

// ---------------- Kernel 3: int8 GEMM + dequant (main path) -----------------
// 256 threads = 4 waves. Block tile 128M x 128N; wave tile 32M x 128N.
// B (64 KB) staged in fragment order via global_load_lds; A read as int8
// dwordx4 straight from x8 (16 full 64B lines per instr).
__global__ __launch_bounds__(256, 2) void gemm8_kernel(
    const signed char* __restrict__ x8, const signed char* __restrict__ w,
    const float* __restrict__ wscale, const unsigned int* __restrict__ ws,
    float* __restrict__ out) {
    __shared__ signed char Blds[64 * 1024];

    const int wave = threadIdx.x >> 6;
    const int lane = threadIdx.x & 63;
    const int quad = lane >> 4;
    const int l16  = lane & 15;

    // XCD swizzle: all 4 N-blocks of one M-strip on one XCD.
    const int id  = blockIdx.x;
    const int xcd = id & 7;
    const int j   = id >> 3;
    const int by  = xcd * 64 + (j >> 2);
    const int bx  = j & 3;
    const int m0 = by * 128;
    const int n0 = bx * 128;

    // stage B: fragment order [c=k/64][t][lane][16B]
    #pragma unroll
    for (int cc = 0; cc < 2; ++cc) {
        int c = wave * 2 + cc;
        #pragma unroll
        for (int t = 0; t < 8; ++t) {
            const signed char* g = w + (long)(n0 + t * 16 + l16) * K_DIM
                                     + c * 64 + quad * 16;
            __builtin_amdgcn_global_load_lds(
                (const __attribute__((address_space(1))) unsigned int*)g,
                (__attribute__((address_space(3))) unsigned int*)(Blds + (c * 8 + t) * 1024),
                16, 0, 0);
        }
    }

    const float s = __uint_as_float(ws[0]);      // published by quant_kernel

    const int mw = m0 + wave * 32;
    const signed char* xr0 = x8 + (long)(mw + l16) * K_DIM + quad * 16;
    const signed char* xr1 = xr0 + (long)16 * K_DIM;

    int32x4 acc0[8] = {};
    int32x4 acc1[8] = {};

    __syncthreads();

    #pragma unroll
    for (int k0 = 0; k0 < K_DIM; k0 += 64) {
        int32x4 a0 = *(const int32x4*)(xr0 + k0);
        int32x4 a1 = *(const int32x4*)(xr1 + k0);
        const signed char* bbase = Blds + (k0 >> 6) * 8192 + lane * 16;
        #pragma unroll
        for (int t = 0; t < 8; ++t) {
            int32x4 b = *(const int32x4*)(bbase + t * 1024);
            acc0[t] = __builtin_amdgcn_mfma_i32_16x16x64_i8(a0, b, acc0[t], 0, 0, 0);
            acc1[t] = __builtin_amdgcn_mfma_i32_16x16x64_i8(a1, b, acc1[t], 0, 0, 0);
        }
    }

    #pragma unroll
    for (int t = 0; t < 8; ++t) {
        int n = n0 + t * 16 + l16;
        float c = s * wscale[n];
        float* o0 = out + (long)(mw + quad * 4) * N_DIM + n;
        float* o1 = o0 + (long)16 * N_DIM;
        #pragma unroll
        for (int r = 0; r < 4; ++r) {
            o0[(long)r * N_DIM] = (float)acc0[t][r] * c;
            o1[(long)r * N_DIM] = (float)acc1[t][r] * c;
        }
    }
}

// ---------------- Fallback gemm (R4): fp32 x, quantize in-loop --------------
__global__ __launch_bounds__(256, 2) void gemm_f32_kernel(
    const float* __restrict__ x, const signed char* __restrict__ w,
    const float* __restrict__ wscale, const unsigned int* __restrict__ ws,
    float* __restrict__ out) {
    __shared__ signed char Blds[64 * 1024];

    const int wave = threadIdx.x >> 6;
    const int lane = threadIdx.x & 63;
    const int quad = lane >> 4;
    const int l16  = lane & 15;

    const int id  = blockIdx.x;
    const int xcd = id & 7;
    const int j   = id >> 3;
    const int by  = xcd * 64 + (j >> 2);
    const int bx  = j & 3;
    const int m0 = by * 128;
    const int n0 = bx * 128;

    #pragma unroll
    for (int cc = 0; cc < 2; ++cc) {
        int c = wave * 2 + cc;
        #pragma unroll
        for (int t = 0; t < 8; ++t) {
            const signed char* g = w + (long)(n0 + t * 16 + l16) * K_DIM
                                     + c * 64 + quad * 16;
            __builtin_amdgcn_global_load_lds(
                (const __attribute__((address_space(1))) unsigned int*)g,
                (__attribute__((address_space(3))) unsigned int*)(Blds + (c * 8 + t) * 1024),
                16, 0, 0);
        }
    }

    float mx  = __uint_as_float(ws[0]);
    float s   = fmaxf(mx / 127.0f, EPSF);
    float inv = 1.0f / s;

    const int mw = m0 + wave * 32;
    const float* xr0 = x + (long)(mw + l16) * K_DIM + quad * 16;
    const float* xr1 = xr0 + (long)16 * K_DIM;

    int32x4 acc0[8] = {};
    int32x4 acc1[8] = {};

    __syncthreads();

    #pragma unroll
    for (int k0 = 0; k0 < K_DIM; k0 += 64) {
        const float4* xp0 = (const float4*)(xr0 + k0);
        const float4* xp1 = (const float4*)(xr1 + k0);
        float4 f0 = xp0[0], f1 = xp0[1], f2 = xp0[2], f3 = xp0[3];
        float4 g0 = xp1[0], g1 = xp1[1], g2 = xp1[2], g3 = xp1[3];
        int32x4 a0, a1;
        a0.x = (int)quantpack4(f0, inv);
        a0.y = (int)quantpack4(f1, inv);
        a0.z = (int)quantpack4(f2, inv);
        a0.w = (int)quantpack4(f3, inv);
        a1.x = (int)quantpack4(g0, inv);
        a1.y = (int)quantpack4(g1, inv);
        a1.z = (int)quantpack4(g2, inv);
        a1.w = (int)quantpack4(g3, inv);

        const signed char* bbase = Blds + (k0 >> 6) * 8192 + lane * 16;
        #pragma unroll
        for (int t = 0; t < 8; ++t) {
            int32x4 b = *(const int32x4*)(bbase + t * 1024);
            acc0[t] = __builtin_amdgcn_mfma_i32_16x16x64_i8(a0, b, acc0[t], 0, 0, 0);
            acc1[t] = __builtin_amdgcn_mfma_i32_16x16x64_i8(a1, b, acc1[t], 0, 0, 0);
        }
    }

    #pragma unroll
    for (int t = 0; t < 8; ++t) {
        int n = n0 + t * 16 + l16;
        float c = s * wscale[n];
        float* o0 = out + (long)(mw + quad * 4) * N_DIM + n;
        float* o1 = o0 + (long)16 * N_DIM;
        #pragma unroll
        for (int r = 0; r < 4; ++r) {
            o0[(long)r * N_DIM] = (float)acc0[t][r] * c;
            o1[(long)r * N_DIM] = (float)acc1[t][r] * c;
        }
    }
}

extern "C" void kernel_launch(void* const* d_in, const int* in_sizes, int n_in,
                              void* d_out, int out_size, void* d_ws, size_t ws_size,
                              hipStream_t stream) {
    const float* x   = (const float*)d_in[0];
    const int*   wi  = (const int*)d_in[1];    // int8 values stored as int32
    const float* sc  = (const float*)d_in[2];
    float*       out = (float*)d_out;

    unsigned int* ws_abs   = (unsigned int*)d_ws;
    float*        partials = (float*)((char*)d_ws + WS_PART);
    unsigned int* wp       = (unsigned int*)((char*)d_ws + WS_WPACK);
    unsigned int* x8       = (unsigned int*)((char*)d_ws + WS_X8);
    const signed char* w8  = (const signed char*)wp;

    absmax1_pack_kernel<<<4160, 256, 0, stream>>>(x, wi, partials, wp);

    if (ws_size >= WS_NEEDED) {
        quant_kernel<<<2048, 256, 0, stream>>>(x, partials, ws_abs, x8);
        gemm8_kernel<<<2048, 256, 0, stream>>>((const signed char*)x8, w8, sc,
                                               ws_abs, out);
    } else {
        absmax2_kernel<<<1, 256, 0, stream>>>(partials, ws_abs);
        gemm_f32_kernel<<<2048, 256, 0, stream>>>(x, w8, sc, ws_abs, out);
    }
}